// Round 3
// baseline (189.678 us; speedup 1.0000x reference)
//
#include <hip/hip_runtime.h>

#define FOLD  8
#define ISIZE 256
#define IN_F  2048
#define OUT_F 2048
#define TBM   32                  // batch rows per block
#define NBLK  (8192 / TBM)        // 256 blocks, 1 per CU (141KB LDS forces 1/CU)
#define CHW   1104                // ushorts per (fold,ks) chunk (2x544 + 16 pad)

typedef __attribute__((ext_vector_type(8))) short short8;   // 8 bf16 (4 VGPRs)
typedef __attribute__((ext_vector_type(4))) float f32x4;    // MFMA C/D frag

// round-to-nearest-even fp32 -> bf16
__device__ __forceinline__ unsigned f2bf(float f) {
    unsigned u = __float_as_uint(f);
    u += 0x7FFFu + ((u >> 16) & 1u);
    return (u >> 16);
}

// ---------------------------------------------------------------------------
// Fallback kernel 1: abs-max. grid*256 threads, `quota` float4 each.
// ---------------------------------------------------------------------------
__global__ __launch_bounds__(256)
void absmax_kernel(const float4* __restrict__ in,
                   float* __restrict__ partials,
                   unsigned int* __restrict__ scal,
                   int quota, int mode) {
    const int nthreads = gridDim.x * 256;
    const int idx = blockIdx.x * 256 + threadIdx.x;
    float m = 0.f;
    #pragma unroll 4
    for (int q = 0; q < quota; ++q) {
        float4 a = in[idx + q * nthreads];
        m = fmaxf(m, fmaxf(fmaxf(fabsf(a.x), fabsf(a.y)),
                           fmaxf(fabsf(a.z), fabsf(a.w))));
    }
    #pragma unroll
    for (int off = 32; off > 0; off >>= 1)
        m = fmaxf(m, __shfl_down(m, off, 64));
    __shared__ float sm[4];
    int lane = threadIdx.x & 63, wv = threadIdx.x >> 6;
    if (lane == 0) sm[wv] = m;
    __syncthreads();
    if (threadIdx.x == 0) {
        float r = fmaxf(fmaxf(sm[0], sm[1]), fmaxf(sm[2], sm[3]));
        if (mode) partials[blockIdx.x] = r;
        else      atomicMax(scal, __float_as_uint(r));
    }
}

// ---------------------------------------------------------------------------
// Fallback kernel 2: W fp32 -> bf16 in MFMA B-fragment order.
// chunk wid=(i*16+nt)*8+ks: B[k=q*8+j][n=lane&15]=W[i][nt*16+n][ks*32+q*8+j]
// ---------------------------------------------------------------------------
__global__ void convert_w_kernel(const float* __restrict__ W,
                                 unsigned short* __restrict__ wsw) {
    int t    = blockIdx.x * 256 + threadIdx.x;
    int wid  = t >> 6;
    int lane = t & 63;
    int i  = wid >> 7;
    int nt = (wid >> 3) & 15;
    int ks = wid & 7;
    int n = lane & 15, q = lane >> 4;
    const float* src = W + (((size_t)i * 256 + nt * 16 + n) * 256 + ks * 32 + q * 8);
    float4 s0 = *(const float4*)(src);
    float4 s1 = *(const float4*)(src + 4);
    uint4 p;
    p.x = f2bf(s0.x) | (f2bf(s0.y) << 16);
    p.y = f2bf(s0.z) | (f2bf(s0.w) << 16);
    p.z = f2bf(s1.x) | (f2bf(s1.y) << 16);
    p.w = f2bf(s1.z) | (f2bf(s1.w) << 16);
    *(uint4*)(wsw + (size_t)wid * 512 + lane * 8) = p;
}

// ---------------------------------------------------------------------------
// Main body shared by fused & fallback paths (verified, unchanged).
// Phase A : masked fold-sum (fp32, reference op order) -> ylds (A-frag order)
// Phase B : wave = (fold, nt-half): 8 nt-tiles x 8 kk x 2 m-tiles MFMA
// ylds ushort idx = (fi*8+ks)*CHW + (row>>4)*544 + q*136 + (row&15)*8 + j
// ---------------------------------------------------------------------------
__device__ __forceinline__ void fold_body(const float* __restrict__ in,
                                          const unsigned short* __restrict__ wsw,
                                          const float* __restrict__ pe,
                                          const float* __restrict__ mn,
                                          const float* __restrict__ mx,
                                          float c, int row0,
                                          unsigned short* ylds,
                                          float* __restrict__ out) {
    const int tid  = threadIdx.x;
    const int lane = tid & 63;
    const int wv   = tid >> 6;

    // ---- Phase A ----
    {
        const int kp  = tid & 127;      // k-pair: k0 = 2*kp
        const int rq  = tid >> 7;       // row quarter-of-8: rows rq*4..rq*4+3
        const int k0  = kp * 2;
        const int jh  = kp & 3;
        const int qA  = (kp >> 2) & 3;
        const int ksA = kp >> 4;

        float pef[FOLD][2], lo[FOLD][2], hi[FOLD][2];
        #pragma unroll
        for (int f = 0; f < FOLD; ++f) {
            float2 p2 = *(const float2*)(pe + f * ISIZE + k0);
            pef[f][0] = p2.x; pef[f][1] = p2.y;
        }
        #pragma unroll
        for (int i = 0; i < FOLD; ++i) {
            float2 a2 = *(const float2*)(mn + i * ISIZE + k0);
            float2 b2 = *(const float2*)(mx + i * ISIZE + k0);
            lo[i][0] = a2.x * c; lo[i][1] = a2.y * c;
            hi[i][0] = b2.x * c; hi[i][1] = b2.y * c;
        }

        #pragma unroll
        for (int r4 = 0; r4 < 4; ++r4) {
            const int row = rq * 4 + r4;
            const float* rowp = in + (size_t)(row0 + row) * IN_F + k0;
            float2 xr[FOLD];
            #pragma unroll
            for (int f = 0; f < FOLD; ++f) xr[f] = *(const float2*)(rowp + f * ISIZE);

            float acc[FOLD][2];
            #pragma unroll
            for (int i = 0; i < FOLD; ++i) { acc[i][0] = 0.0f; acc[i][1] = 0.0f; }
            #pragma unroll
            for (int f = 0; f < FOLD; ++f) {
                float xv0 = fminf(fmaxf(xr[f].x, -c), c) + pef[f][0];
                float xv1 = fminf(fmaxf(xr[f].y, -c), c) + pef[f][1];
                #pragma unroll
                for (int i = 0; i < FOLD; ++i) {
                    if (xv0 >= lo[i][0] && xv0 <= hi[i][0]) acc[i][0] += xv0;
                    if (xv1 >= lo[i][1] && xv1 <= hi[i][1]) acc[i][1] += xv1;
                }
            }
            const unsigned base = (unsigned)((row >> 4) * 544 + qA * 136 + (row & 15) * 8 + jh * 2);
            #pragma unroll
            for (int i = 0; i < FOLD; ++i) {
                unsigned us = f2bf(acc[i][0]) | (f2bf(acc[i][1]) << 16);
                *(unsigned*)&ylds[(i * 8 + ksA) * CHW + base] = us;
            }
        }
    }
    __syncthreads();

    // ---- Phase B ---- wave = (fold, nt-half)
    {
        const int fi   = wv >> 1;
        const int nh   = wv & 1;
        const int mrow = lane & 15;
        const int quad = lane >> 4;

        // cache this fold's 16 A-fragments (8 k-steps x 2 m-tiles): 64 VGPRs
        short8 afr[8][2];
        #pragma unroll
        for (int kk = 0; kk < 8; ++kk) {
            #pragma unroll
            for (int mt = 0; mt < 2; ++mt)
                afr[kk][mt] = *(const short8*)&ylds[(fi * 8 + kk) * CHW + mt * 544 + quad * 136 + mrow * 8];
        }

        const int col0 = fi * 256 + mrow;
        #pragma unroll 2
        for (int nt8 = 0; nt8 < 8; ++nt8) {
            const int ntg = nh * 8 + nt8;
            f32x4 a0 = (f32x4){0.f, 0.f, 0.f, 0.f};
            f32x4 a1 = (f32x4){0.f, 0.f, 0.f, 0.f};
            const unsigned short* wb = wsw + ((size_t)(fi * 16 + ntg) * 8) * 512 + lane * 8;
            uint4 wq[8];
            #pragma unroll
            for (int kk = 0; kk < 8; ++kk) wq[kk] = *(const uint4*)(wb + kk * 512);
            #pragma unroll
            for (int kk = 0; kk < 8; ++kk) {
                union { uint4 u; short8 s; } cv; cv.u = wq[kk];
                a0 = __builtin_amdgcn_mfma_f32_16x16x32_bf16(afr[kk][0], cv.s, a0, 0, 0, 0);
                a1 = __builtin_amdgcn_mfma_f32_16x16x32_bf16(afr[kk][1], cv.s, a1, 0, 0, 0);
            }
            // C/D layout: col=lane&15, row=quad*4+reg; m-tile 1 is rows +16
            #pragma unroll
            for (int rg = 0; rg < 4; ++rg) {
                out[(size_t)(row0 +      quad * 4 + rg) * OUT_F + col0 + ntg * 16] = a0[rg];
                out[(size_t)(row0 + 16 + quad * 4 + rg) * OUT_F + col0 + ntg * 16] = a1[rg];
            }
        }
    }
}

// ---------------------------------------------------------------------------
// Fused single-dispatch kernel with a MANUAL device-scope grid barrier.
// No cooperative launch (graph-capture-safe plain <<<>>> launch).
// Residency guarantee: 141KB LDS -> 1 block/CU; grid = 256 = CU count.
// counter is zeroed by a captured hipMemsetAsync before this kernel.
// Bounded spin (~28ms) turns any residency failure into a wrong answer
// (diagnosable) rather than a hung container.
// ---------------------------------------------------------------------------
__global__ __launch_bounds__(1024, 1)
void fused_spin(const float* __restrict__ in,
                const float* __restrict__ W,
                unsigned short* __restrict__ wsw,
                const float* __restrict__ pe,
                const float* __restrict__ mn,
                const float* __restrict__ mx,
                unsigned int* __restrict__ counter,
                float* __restrict__ partials,
                float* __restrict__ out) {
    __shared__ __align__(16) unsigned short ylds[64 * CHW];   // 141,312 B
    __shared__ float sred[16];

    const int tid  = threadIdx.x;
    const int lane = tid & 63;
    const int wv   = tid >> 6;
    const int row0 = blockIdx.x * TBM;

    // ---- Step 0a: abs-max over this block's own 32 rows (256 KB) ----
    {
        const float4* in4 = (const float4*)(in + (size_t)row0 * IN_F);
        float m = 0.f;
        #pragma unroll 4
        for (int q = 0; q < 16; ++q) {
            float4 a = in4[tid + q * 1024];
            m = fmaxf(m, fmaxf(fmaxf(fabsf(a.x), fabsf(a.y)),
                               fmaxf(fabsf(a.z), fabsf(a.w))));
        }
        #pragma unroll
        for (int off = 32; off > 0; off >>= 1)
            m = fmaxf(m, __shfl_down(m, off, 64));
        if (lane == 0) sred[wv] = m;
    }

    // ---- Step 0b: blocks 0..63 convert W -> bf16 B-fragments.
    // Agent-scope 8B stores: bypass non-coherent per-XCD caching so
    // readers on other XCDs observe fresh data after the barrier.
    if (blockIdx.x < 64) {
        const int g    = blockIdx.x * 1024 + tid;   // same map as convert_w
        const int wid  = g >> 6;
        const int l    = g & 63;
        const int i  = wid >> 7;
        const int nt = (wid >> 3) & 15;
        const int ks = wid & 7;
        const int n = l & 15, q = l >> 4;
        const float* src = W + (((size_t)i * 256 + nt * 16 + n) * 256 + ks * 32 + q * 8);
        float4 s0 = *(const float4*)(src);
        float4 s1 = *(const float4*)(src + 4);
        unsigned long long w0 = (unsigned long long)(f2bf(s0.x) | (f2bf(s0.y) << 16))
                              | ((unsigned long long)(f2bf(s0.z) | (f2bf(s0.w) << 16)) << 32);
        unsigned long long w1 = (unsigned long long)(f2bf(s1.x) | (f2bf(s1.y) << 16))
                              | ((unsigned long long)(f2bf(s1.z) | (f2bf(s1.w) << 16)) << 32);
        unsigned long long* dst = (unsigned long long*)(wsw + (size_t)wid * 512 + l * 8);
        __hip_atomic_store(&dst[0], w0, __ATOMIC_RELAXED, __HIP_MEMORY_SCOPE_AGENT);
        __hip_atomic_store(&dst[1], w1, __ATOMIC_RELAXED, __HIP_MEMORY_SCOPE_AGENT);
    }

    __syncthreads();   // all block stores drained (vmcnt) + sred visible

    // ---- grid barrier: publish partial, arrive, spin ----
    if (tid == 0) {
        float r = sred[0];
        #pragma unroll
        for (int i = 1; i < 16; ++i) r = fmaxf(r, sred[i]);
        __hip_atomic_store(&partials[blockIdx.x], r, __ATOMIC_RELAXED, __HIP_MEMORY_SCOPE_AGENT);
        __threadfence();   // agent fence: L2 writeback, cross-XCD visibility
        __hip_atomic_fetch_add(counter, 1u, __ATOMIC_RELEASE, __HIP_MEMORY_SCOPE_AGENT);
        for (int it = 0; it < (1 << 20); ++it) {   // bounded: ~28 ms worst case
            unsigned v = __hip_atomic_load(counter, __ATOMIC_ACQUIRE, __HIP_MEMORY_SCOPE_AGENT);
            if (v >= NBLK) break;
            __builtin_amdgcn_s_sleep(1);
        }
    }
    __syncthreads();

    // ---- global abs-max from 256 partials ----
    float mabs;
    {
        float v = (tid < NBLK)
            ? __hip_atomic_load(&partials[tid], __ATOMIC_RELAXED, __HIP_MEMORY_SCOPE_AGENT)
            : 0.0f;
        #pragma unroll
        for (int off = 32; off > 0; off >>= 1)
            v = fmaxf(v, __shfl_down(v, off, 64));
        if (lane == 0) sred[wv] = v;
        __syncthreads();
        float r = sred[0];
        #pragma unroll
        for (int i = 1; i < 16; ++i) r = fmaxf(r, sred[i]);
        mabs = r;
    }
    const float c = (mabs / 127.0f) * 127.0f;   // reference fp32 op order

    fold_body(in, wsw, pe, mn, mx, c, row0, ylds, out);
}

// ---------------------------------------------------------------------------
// Fallback main kernel (3-dispatch path), identical to round-0 verified best.
// ---------------------------------------------------------------------------
template<int PRECONV>
__global__ __launch_bounds__(1024, 1)
void fold_main(const float* __restrict__ in,
               const float* __restrict__ W,
               const unsigned short* __restrict__ wsw,
               const float* __restrict__ pe,
               const float* __restrict__ mn,
               const float* __restrict__ mx,
               const float* __restrict__ partials,
               const unsigned int* __restrict__ scal,
               int npart,
               float* __restrict__ out) {
    __shared__ __align__(16) unsigned short ylds[64 * CHW];   // 141,312 B
    __shared__ float sred[16];

    const int tid  = threadIdx.x;
    const int lane = tid & 63;
    const int wv   = tid >> 6;          // 0..15
    const int row0 = blockIdx.x * TBM;

    // ---- global abs-max ----
    float mabs;
    if (npart > 0) {
        float v = (tid < npart) ? partials[tid] : 0.0f;
        #pragma unroll
        for (int off = 32; off > 0; off >>= 1)
            v = fmaxf(v, __shfl_down(v, off, 64));
        if (lane == 0) sred[wv] = v;
        __syncthreads();
        float r = sred[0];
        #pragma unroll
        for (int i = 1; i < 16; ++i) r = fmaxf(r, sred[i]);
        mabs = r;
    } else {
        mabs = __uint_as_float(*scal);
    }
    const float c = (mabs / 127.0f) * 127.0f;   // reference fp32 op order

    if (PRECONV) {
        fold_body(in, wsw, pe, mn, mx, c, row0, ylds, out);
    } else {
        // ---- Phase A (same as fold_body) ----
        {
            const int kp  = tid & 127;
            const int rq  = tid >> 7;
            const int k0  = kp * 2;
            const int jh  = kp & 3;
            const int qA  = (kp >> 2) & 3;
            const int ksA = kp >> 4;

            float pef[FOLD][2], lo[FOLD][2], hi[FOLD][2];
            #pragma unroll
            for (int f = 0; f < FOLD; ++f) {
                float2 p2 = *(const float2*)(pe + f * ISIZE + k0);
                pef[f][0] = p2.x; pef[f][1] = p2.y;
            }
            #pragma unroll
            for (int i = 0; i < FOLD; ++i) {
                float2 a2 = *(const float2*)(mn + i * ISIZE + k0);
                float2 b2 = *(const float2*)(mx + i * ISIZE + k0);
                lo[i][0] = a2.x * c; lo[i][1] = a2.y * c;
                hi[i][0] = b2.x * c; hi[i][1] = b2.y * c;
            }

            #pragma unroll
            for (int r4 = 0; r4 < 4; ++r4) {
                const int row = rq * 4 + r4;
                const float* rowp = in + (size_t)(row0 + row) * IN_F + k0;
                float2 xr[FOLD];
                #pragma unroll
                for (int f = 0; f < FOLD; ++f) xr[f] = *(const float2*)(rowp + f * ISIZE);

                float acc[FOLD][2];
                #pragma unroll
                for (int i = 0; i < FOLD; ++i) { acc[i][0] = 0.0f; acc[i][1] = 0.0f; }
                #pragma unroll
                for (int f = 0; f < FOLD; ++f) {
                    float xv0 = fminf(fmaxf(xr[f].x, -c), c) + pef[f][0];
                    float xv1 = fminf(fmaxf(xr[f].y, -c), c) + pef[f][1];
                    #pragma unroll
                    for (int i = 0; i < FOLD; ++i) {
                        if (xv0 >= lo[i][0] && xv0 <= hi[i][0]) acc[i][0] += xv0;
                        if (xv1 >= lo[i][1] && xv1 <= hi[i][1]) acc[i][1] += xv1;
                    }
                }
                const unsigned base = (unsigned)((row >> 4) * 544 + qA * 136 + (row & 15) * 8 + jh * 2);
                #pragma unroll
                for (int i = 0; i < FOLD; ++i) {
                    unsigned us = f2bf(acc[i][0]) | (f2bf(acc[i][1]) << 16);
                    *(unsigned*)&ylds[(i * 8 + ksA) * CHW + base] = us;
                }
            }
        }
        __syncthreads();

        // ---- Phase B with on-the-fly W conversion ----
        {
            const int fi   = wv >> 1;
            const int nh   = wv & 1;
            const int mrow = lane & 15;
            const int quad = lane >> 4;

            short8 afr[8][2];
            #pragma unroll
            for (int kk = 0; kk < 8; ++kk) {
                #pragma unroll
                for (int mt = 0; mt < 2; ++mt)
                    afr[kk][mt] = *(const short8*)&ylds[(fi * 8 + kk) * CHW + mt * 544 + quad * 136 + mrow * 8];
            }

            const int col0 = fi * 256 + mrow;
            #pragma unroll 2
            for (int nt8 = 0; nt8 < 8; ++nt8) {
                const int ntg = nh * 8 + nt8;
                f32x4 a0 = (f32x4){0.f, 0.f, 0.f, 0.f};
                f32x4 a1 = (f32x4){0.f, 0.f, 0.f, 0.f};
                const float* wb = W + ((size_t)(fi * 256 + ntg * 16 + mrow) * 256 + quad * 8);
                float4 w[16];
                #pragma unroll
                for (int kk = 0; kk < 8; ++kk) {
                    w[2 * kk]     = *(const float4*)(wb + kk * 32);
                    w[2 * kk + 1] = *(const float4*)(wb + kk * 32 + 4);
                }
                #pragma unroll
                for (int kk = 0; kk < 8; ++kk) {
                    union { uint4 u; short8 s; } cv;
                    cv.u.x = f2bf(w[2*kk].x)   | (f2bf(w[2*kk].y)   << 16);
                    cv.u.y = f2bf(w[2*kk].z)   | (f2bf(w[2*kk].w)   << 16);
                    cv.u.z = f2bf(w[2*kk+1].x) | (f2bf(w[2*kk+1].y) << 16);
                    cv.u.w = f2bf(w[2*kk+1].z) | (f2bf(w[2*kk+1].w) << 16);
                    a0 = __builtin_amdgcn_mfma_f32_16x16x32_bf16(afr[kk][0], cv.s, a0, 0, 0, 0);
                    a1 = __builtin_amdgcn_mfma_f32_16x16x32_bf16(afr[kk][1], cv.s, a1, 0, 0, 0);
                }
                #pragma unroll
                for (int rg = 0; rg < 4; ++rg) {
                    out[(size_t)(row0 +      quad * 4 + rg) * OUT_F + col0 + ntg * 16] = a0[rg];
                    out[(size_t)(row0 + 16 + quad * 4 + rg) * OUT_F + col0 + ntg * 16] = a1[rg];
                }
            }
        }
    }
}

extern "C" void kernel_launch(void* const* d_in, const int* in_sizes, int n_in,
                              void* d_out, int out_size, void* d_ws, size_t ws_size,
                              hipStream_t stream) {
    const float* in = (const float*)d_in[0];   // [8192, 2048]
    const float* W  = (const float*)d_in[1];   // [8, 256, 256]
    const float* pe = (const float*)d_in[2];   // [1, 8, 256]
    const float* mn = (const float*)d_in[3];   // [1, 8, 256]
    const float* mx = (const float*)d_in[4];   // [1, 8, 256]
    float* out = (float*)d_out;                // [8192, 2048]

    const size_t PART_OFF  = 16;               // fallback-path partials
    const size_t PART2_OFF = 512;              // fused-path partials (own lines)
    const size_t WSW_OFF   = 8192;
    const size_t WSW_BYTES = (size_t)FOLD * 256 * 256 * 2;   // 1 MB

    unsigned int*   scal     = (unsigned int*)d_ws;          // also fused counter
    float*          partials = (float*)((char*)d_ws + PART_OFF);
    float*          part2    = (float*)((char*)d_ws + PART2_OFF);
    unsigned short* wsw      = (unsigned short*)((char*)d_ws + WSW_OFF);

    const bool preconv = ws_size >= WSW_OFF + WSW_BYTES;

    if (preconv) {
        // zero the barrier counter (captured into the graph; runs every replay)
        hipMemsetAsync(d_ws, 0, 64, stream);
        fused_spin<<<NBLK, 1024, 0, stream>>>(in, W, wsw, pe, mn, mx,
                                              (unsigned int*)d_ws, part2, out);
        return;
    }

    int npart;
    if (ws_size >= PART_OFF + 1024 * sizeof(float)) {          // 4112 B
        absmax_kernel<<<1024, 256, 0, stream>>>((const float4*)in, partials, scal, 16, 1);
        npart = 1024;
    } else if (ws_size >= PART_OFF + 256 * sizeof(float)) {    // 1040 B
        absmax_kernel<<<256, 256, 0, stream>>>((const float4*)in, partials, scal, 64, 1);
        npart = 256;
    } else {
        hipMemsetAsync(d_ws, 0, sizeof(unsigned int), stream);
        absmax_kernel<<<256, 256, 0, stream>>>((const float4*)in, partials, scal, 64, 0);
        npart = 0;
    }
    fold_main<0><<<NBLK, 1024, 0, stream>>>(in, W, wsw, pe, mn, mx,
                                            partials, scal, npart, out);
}

// Round 4
// 150.752 us; speedup vs baseline: 1.2582x; 1.2582x over previous
//
#include <hip/hip_runtime.h>

#define FOLD  8
#define ISIZE 256
#define IN_F  2048
#define OUT_F 2048

// ---- main-path geometry: 512 blocks x 512 threads, 16 rows/block, 2 blk/CU
#define TBM2  16
#define NBLK2 (8192 / TBM2)       // 512
#define CHW2  560                 // ushorts per (fold,ks) chunk (544 + 16 pad)

// ---- fallback geometry (round-0 verified): 256 x 1024, 32 rows/block
#define TBM   32
#define NBLK  (8192 / TBM)
#define CHW   1104

typedef __attribute__((ext_vector_type(8))) short short8;   // 8 bf16 (4 VGPRs)
typedef __attribute__((ext_vector_type(4))) float f32x4;    // MFMA C/D frag

// round-to-nearest-even fp32 -> bf16
__device__ __forceinline__ unsigned f2bf(float f) {
    unsigned u = __float_as_uint(f);
    u += 0x7FFFu + ((u >> 16) & 1u);
    return (u >> 16);
}

// ---------------------------------------------------------------------------
// Kernel 1 (main path): abs-max partials over `quota` float4/thread, PLUS
// blocks 0..255 convert W fp32 -> bf16 in MFMA B-fragment order (same map
// as the verified convert_w_kernel). Convert adds ~1us inside a BW-bound
// scan; saves a dispatch.
// chunk wid=(i*16+nt)*8+ks: B[k=q*8+j][n=lane&15]=W[i][nt*16+n][ks*32+q*8+j]
// ---------------------------------------------------------------------------
__global__ __launch_bounds__(256)
void absmax_conv(const float4* __restrict__ in,
                 const float* __restrict__ W,
                 float* __restrict__ partials,
                 unsigned short* __restrict__ wsw,
                 int quota) {
    const int nthreads = gridDim.x * 256;
    const int idx = blockIdx.x * 256 + threadIdx.x;

    // W conversion for the first 256 blocks (65536 threads = full W)
    if (blockIdx.x < 256) {
        const int t    = blockIdx.x * 256 + threadIdx.x;
        const int wid  = t >> 6;
        const int l    = t & 63;
        const int i  = wid >> 7;
        const int nt = (wid >> 3) & 15;
        const int ks = wid & 7;
        const int n = l & 15, q = l >> 4;
        const float* src = W + (((size_t)i * 256 + nt * 16 + n) * 256 + ks * 32 + q * 8);
        float4 s0 = *(const float4*)(src);
        float4 s1 = *(const float4*)(src + 4);
        uint4 p;
        p.x = f2bf(s0.x) | (f2bf(s0.y) << 16);
        p.y = f2bf(s0.z) | (f2bf(s0.w) << 16);
        p.z = f2bf(s1.x) | (f2bf(s1.y) << 16);
        p.w = f2bf(s1.z) | (f2bf(s1.w) << 16);
        *(uint4*)(wsw + (size_t)wid * 512 + l * 8) = p;
    }

    float m = 0.f;
    #pragma unroll 4
    for (int q = 0; q < quota; ++q) {
        float4 a = in[idx + q * nthreads];
        m = fmaxf(m, fmaxf(fmaxf(fabsf(a.x), fabsf(a.y)),
                           fmaxf(fabsf(a.z), fabsf(a.w))));
    }
    #pragma unroll
    for (int off = 32; off > 0; off >>= 1)
        m = fmaxf(m, __shfl_down(m, off, 64));
    __shared__ float sm[4];
    int lane = threadIdx.x & 63, wv = threadIdx.x >> 6;
    if (lane == 0) sm[wv] = m;
    __syncthreads();
    if (threadIdx.x == 0)
        partials[blockIdx.x] = fmaxf(fmaxf(sm[0], sm[1]), fmaxf(sm[2], sm[3]));
}

// ---------------------------------------------------------------------------
// Fallback kernel 1: plain abs-max (atomicMax or partials).
// ---------------------------------------------------------------------------
__global__ __launch_bounds__(256)
void absmax_kernel(const float4* __restrict__ in,
                   float* __restrict__ partials,
                   unsigned int* __restrict__ scal,
                   int quota, int mode) {
    const int nthreads = gridDim.x * 256;
    const int idx = blockIdx.x * 256 + threadIdx.x;
    float m = 0.f;
    #pragma unroll 4
    for (int q = 0; q < quota; ++q) {
        float4 a = in[idx + q * nthreads];
        m = fmaxf(m, fmaxf(fmaxf(fabsf(a.x), fabsf(a.y)),
                           fmaxf(fabsf(a.z), fabsf(a.w))));
    }
    #pragma unroll
    for (int off = 32; off > 0; off >>= 1)
        m = fmaxf(m, __shfl_down(m, off, 64));
    __shared__ float sm[4];
    int lane = threadIdx.x & 63, wv = threadIdx.x >> 6;
    if (lane == 0) sm[wv] = m;
    __syncthreads();
    if (threadIdx.x == 0) {
        float r = fmaxf(fmaxf(sm[0], sm[1]), fmaxf(sm[2], sm[3]));
        if (mode) partials[blockIdx.x] = r;
        else      atomicMax(scal, __float_as_uint(r));
    }
}

// ---------------------------------------------------------------------------
// Main kernel v2: 512 blocks x 512 threads (8 waves), 16 rows per block.
// LDS 71.7 KB -> 2 blocks/CU so block n+1 Phase A (VALU+loads) overlaps
// block n Phase B (MFMA + L2 wsw reads + stores) on the same CU.
//   Phase A: thread owns k-pair (tid&127), rows (tid>>7)*4..+3 (16 rows)
//            ylds ushort idx = (fi*8+ks)*CHW2 + q*136 + row*8 + j
//   Phase B: wave fi = wv (8 waves = 8 folds); 16 nt-tiles x 8 kk MFMA
// Verified fragment map, m-tile dimension dropped (rows<16 => row>>4==0).
// ---------------------------------------------------------------------------
__global__ __launch_bounds__(512, 4)
void fold2(const float* __restrict__ in,
           const unsigned short* __restrict__ wsw,
           const float* __restrict__ pe,
           const float* __restrict__ mn,
           const float* __restrict__ mx,
           const float* __restrict__ partials,
           int npart,
           float* __restrict__ out) {
    __shared__ __align__(16) unsigned short ylds[64 * CHW2];   // 71,680 B
    __shared__ float sred[8];

    const int tid  = threadIdx.x;
    const int lane = tid & 63;
    const int wv   = tid >> 6;          // 0..7
    const int row0 = blockIdx.x * TBM2;

    // ---- global abs-max from partials ----
    float mabs;
    {
        float v = 0.f;
        for (int p = tid; p < npart; p += 512) v = fmaxf(v, partials[p]);
        #pragma unroll
        for (int off = 32; off > 0; off >>= 1)
            v = fmaxf(v, __shfl_down(v, off, 64));
        if (lane == 0) sred[wv] = v;
        __syncthreads();
        float r = sred[0];
        #pragma unroll
        for (int i = 1; i < 8; ++i) r = fmaxf(r, sred[i]);
        mabs = r;
    }
    const float c = (mabs / 127.0f) * 127.0f;   // reference fp32 op order

    // ---- Phase A ----
    {
        const int kp  = tid & 127;      // k-pair: k0 = 2*kp
        const int rq  = tid >> 7;       // 0..3: rows rq*4..rq*4+3
        const int k0  = kp * 2;
        const int jh  = kp & 3;
        const int qA  = (kp >> 2) & 3;
        const int ksA = kp >> 4;

        float pef[FOLD][2], lo[FOLD][2], hi[FOLD][2];
        #pragma unroll
        for (int f = 0; f < FOLD; ++f) {
            float2 p2 = *(const float2*)(pe + f * ISIZE + k0);
            pef[f][0] = p2.x; pef[f][1] = p2.y;
        }
        #pragma unroll
        for (int i = 0; i < FOLD; ++i) {
            float2 a2 = *(const float2*)(mn + i * ISIZE + k0);
            float2 b2 = *(const float2*)(mx + i * ISIZE + k0);
            lo[i][0] = a2.x * c; lo[i][1] = a2.y * c;
            hi[i][0] = b2.x * c; hi[i][1] = b2.y * c;
        }

        #pragma unroll
        for (int r4 = 0; r4 < 4; ++r4) {
            const int row = rq * 4 + r4;           // 0..15
            const float* rowp = in + (size_t)(row0 + row) * IN_F + k0;
            float2 xr[FOLD];
            #pragma unroll
            for (int f = 0; f < FOLD; ++f) xr[f] = *(const float2*)(rowp + f * ISIZE);

            float acc[FOLD][2];
            #pragma unroll
            for (int i = 0; i < FOLD; ++i) { acc[i][0] = 0.0f; acc[i][1] = 0.0f; }
            #pragma unroll
            for (int f = 0; f < FOLD; ++f) {
                float xv0 = fminf(fmaxf(xr[f].x, -c), c) + pef[f][0];
                float xv1 = fminf(fmaxf(xr[f].y, -c), c) + pef[f][1];
                #pragma unroll
                for (int i = 0; i < FOLD; ++i) {
                    if (xv0 >= lo[i][0] && xv0 <= hi[i][0]) acc[i][0] += xv0;
                    if (xv1 >= lo[i][1] && xv1 <= hi[i][1]) acc[i][1] += xv1;
                }
            }
            const unsigned base = (unsigned)(qA * 136 + row * 8 + jh * 2);
            #pragma unroll
            for (int i = 0; i < FOLD; ++i) {
                unsigned us = f2bf(acc[i][0]) | (f2bf(acc[i][1]) << 16);
                *(unsigned*)&ylds[(i * 8 + ksA) * CHW2 + base] = us;
            }
        }
    }
    __syncthreads();

    // ---- Phase B ---- wave = fold
    {
        const int fi   = wv;
        const int mrow = lane & 15;
        const int quad = lane >> 4;

        // this fold's 8 A-fragments (8 k-steps x 1 m-tile): 32 VGPRs
        short8 afr[8];
        #pragma unroll
        for (int kk = 0; kk < 8; ++kk)
            afr[kk] = *(const short8*)&ylds[(fi * 8 + kk) * CHW2 + quad * 136 + mrow * 8];

        const int col0 = fi * 256 + mrow;
        #pragma unroll 2
        for (int ntg = 0; ntg < 16; ++ntg) {
            f32x4 a0 = (f32x4){0.f, 0.f, 0.f, 0.f};
            const unsigned short* wb = wsw + ((size_t)(fi * 16 + ntg) * 8) * 512 + lane * 8;
            uint4 wq[8];
            #pragma unroll
            for (int kk = 0; kk < 8; ++kk) wq[kk] = *(const uint4*)(wb + kk * 512);
            #pragma unroll
            for (int kk = 0; kk < 8; ++kk) {
                union { uint4 u; short8 s; } cv; cv.u = wq[kk];
                a0 = __builtin_amdgcn_mfma_f32_16x16x32_bf16(afr[kk], cv.s, a0, 0, 0, 0);
            }
            // C/D layout: col=lane&15, row=quad*4+reg
            #pragma unroll
            for (int rg = 0; rg < 4; ++rg)
                out[(size_t)(row0 + quad * 4 + rg) * OUT_F + col0 + ntg * 16] = a0[rg];
        }
    }
}

// ---------------------------------------------------------------------------
// Fallback main kernel (round-0 verified, W converted on the fly).
// ---------------------------------------------------------------------------
__global__ __launch_bounds__(1024, 1)
void fold_main(const float* __restrict__ in,
               const float* __restrict__ W,
               const float* __restrict__ pe,
               const float* __restrict__ mn,
               const float* __restrict__ mx,
               const float* __restrict__ partials,
               const unsigned int* __restrict__ scal,
               int npart,
               float* __restrict__ out) {
    __shared__ __align__(16) unsigned short ylds[64 * CHW];   // 141,312 B
    __shared__ float sred[16];

    const int tid  = threadIdx.x;
    const int lane = tid & 63;
    const int wv   = tid >> 6;          // 0..15
    const int row0 = blockIdx.x * TBM;

    // ---- global abs-max ----
    float mabs;
    if (npart > 0) {
        float v = (tid < npart) ? partials[tid] : 0.0f;
        #pragma unroll
        for (int off = 32; off > 0; off >>= 1)
            v = fmaxf(v, __shfl_down(v, off, 64));
        if (lane == 0) sred[wv] = v;
        __syncthreads();
        float r = sred[0];
        #pragma unroll
        for (int i = 1; i < 16; ++i) r = fmaxf(r, sred[i]);
        mabs = r;
    } else {
        mabs = __uint_as_float(*scal);
    }
    const float c = (mabs / 127.0f) * 127.0f;   // reference fp32 op order

    // ---- Phase A ----
    {
        const int kp  = tid & 127;
        const int rq  = tid >> 7;
        const int k0  = kp * 2;
        const int jh  = kp & 3;
        const int qA  = (kp >> 2) & 3;
        const int ksA = kp >> 4;

        float pef[FOLD][2], lo[FOLD][2], hi[FOLD][2];
        #pragma unroll
        for (int f = 0; f < FOLD; ++f) {
            float2 p2 = *(const float2*)(pe + f * ISIZE + k0);
            pef[f][0] = p2.x; pef[f][1] = p2.y;
        }
        #pragma unroll
        for (int i = 0; i < FOLD; ++i) {
            float2 a2 = *(const float2*)(mn + i * ISIZE + k0);
            float2 b2 = *(const float2*)(mx + i * ISIZE + k0);
            lo[i][0] = a2.x * c; lo[i][1] = a2.y * c;
            hi[i][0] = b2.x * c; hi[i][1] = b2.y * c;
        }

        #pragma unroll
        for (int r4 = 0; r4 < 4; ++r4) {
            const int row = rq * 4 + r4;
            const float* rowp = in + (size_t)(row0 + row) * IN_F + k0;
            float2 xr[FOLD];
            #pragma unroll
            for (int f = 0; f < FOLD; ++f) xr[f] = *(const float2*)(rowp + f * ISIZE);

            float acc[FOLD][2];
            #pragma unroll
            for (int i = 0; i < FOLD; ++i) { acc[i][0] = 0.0f; acc[i][1] = 0.0f; }
            #pragma unroll
            for (int f = 0; f < FOLD; ++f) {
                float xv0 = fminf(fmaxf(xr[f].x, -c), c) + pef[f][0];
                float xv1 = fminf(fmaxf(xr[f].y, -c), c) + pef[f][1];
                #pragma unroll
                for (int i = 0; i < FOLD; ++i) {
                    if (xv0 >= lo[i][0] && xv0 <= hi[i][0]) acc[i][0] += xv0;
                    if (xv1 >= lo[i][1] && xv1 <= hi[i][1]) acc[i][1] += xv1;
                }
            }
            const unsigned base = (unsigned)((row >> 4) * 544 + qA * 136 + (row & 15) * 8 + jh * 2);
            #pragma unroll
            for (int i = 0; i < FOLD; ++i) {
                unsigned us = f2bf(acc[i][0]) | (f2bf(acc[i][1]) << 16);
                *(unsigned*)&ylds[(i * 8 + ksA) * CHW + base] = us;
            }
        }
    }
    __syncthreads();

    // ---- Phase B with on-the-fly W conversion ----
    {
        const int fi   = wv >> 1;
        const int nh   = wv & 1;
        const int mrow = lane & 15;
        const int quad = lane >> 4;

        short8 afr[8][2];
        #pragma unroll
        for (int kk = 0; kk < 8; ++kk) {
            #pragma unroll
            for (int mt = 0; mt < 2; ++mt)
                afr[kk][mt] = *(const short8*)&ylds[(fi * 8 + kk) * CHW + mt * 544 + quad * 136 + mrow * 8];
        }

        const int col0 = fi * 256 + mrow;
        #pragma unroll 2
        for (int nt8 = 0; nt8 < 8; ++nt8) {
            const int ntg = nh * 8 + nt8;
            f32x4 a0 = (f32x4){0.f, 0.f, 0.f, 0.f};
            f32x4 a1 = (f32x4){0.f, 0.f, 0.f, 0.f};
            const float* wb = W + ((size_t)(fi * 256 + ntg * 16 + mrow) * 256 + quad * 8);
            float4 w[16];
            #pragma unroll
            for (int kk = 0; kk < 8; ++kk) {
                w[2 * kk]     = *(const float4*)(wb + kk * 32);
                w[2 * kk + 1] = *(const float4*)(wb + kk * 32 + 4);
            }
            #pragma unroll
            for (int kk = 0; kk < 8; ++kk) {
                union { uint4 u; short8 s; } cv;
                cv.u.x = f2bf(w[2*kk].x)   | (f2bf(w[2*kk].y)   << 16);
                cv.u.y = f2bf(w[2*kk].z)   | (f2bf(w[2*kk].w)   << 16);
                cv.u.z = f2bf(w[2*kk+1].x) | (f2bf(w[2*kk+1].y) << 16);
                cv.u.w = f2bf(w[2*kk+1].z) | (f2bf(w[2*kk+1].w) << 16);
                a0 = __builtin_amdgcn_mfma_f32_16x16x32_bf16(afr[kk][0], cv.s, a0, 0, 0, 0);
                a1 = __builtin_amdgcn_mfma_f32_16x16x32_bf16(afr[kk][1], cv.s, a1, 0, 0, 0);
            }
            #pragma unroll
            for (int rg = 0; rg < 4; ++rg) {
                out[(size_t)(row0 +      quad * 4 + rg) * OUT_F + col0 + ntg * 16] = a0[rg];
                out[(size_t)(row0 + 16 + quad * 4 + rg) * OUT_F + col0 + ntg * 16] = a1[rg];
            }
        }
    }
}

extern "C" void kernel_launch(void* const* d_in, const int* in_sizes, int n_in,
                              void* d_out, int out_size, void* d_ws, size_t ws_size,
                              hipStream_t stream) {
    const float* in = (const float*)d_in[0];   // [8192, 2048]
    const float* W  = (const float*)d_in[1];   // [8, 256, 256]
    const float* pe = (const float*)d_in[2];   // [1, 8, 256]
    const float* mn = (const float*)d_in[3];   // [1, 8, 256]
    const float* mx = (const float*)d_in[4];   // [1, 8, 256]
    float* out = (float*)d_out;                // [8192, 2048]

    const size_t PART_OFF  = 16;
    const size_t WSW_OFF   = 8192;
    const size_t WSW_BYTES = (size_t)FOLD * 256 * 256 * 2;   // 1 MB

    unsigned int*   scal     = (unsigned int*)d_ws;
    float*          partials = (float*)((char*)d_ws + PART_OFF);
    unsigned short* wsw      = (unsigned short*)((char*)d_ws + WSW_OFF);

    const bool preconv = ws_size >= WSW_OFF + WSW_BYTES;

    if (preconv && ws_size >= PART_OFF + 1024 * sizeof(float)) {
        // main path: scan+convert (1 dispatch), then overlap-friendly fold2
        absmax_conv<<<1024, 256, 0, stream>>>((const float4*)in, W, partials, wsw, 16);
        fold2<<<NBLK2, 512, 0, stream>>>(in, wsw, pe, mn, mx, partials, 1024, out);
        return;
    }

    // fallback: round-0 verified two-kernel path (W converted in-kernel)
    int npart;
    if (ws_size >= PART_OFF + 1024 * sizeof(float)) {
        absmax_kernel<<<1024, 256, 0, stream>>>((const float4*)in, partials, scal, 16, 1);
        npart = 1024;
    } else if (ws_size >= PART_OFF + 256 * sizeof(float)) {
        absmax_kernel<<<256, 256, 0, stream>>>((const float4*)in, partials, scal, 64, 1);
        npart = 256;
    } else {
        hipMemsetAsync(d_ws, 0, sizeof(unsigned int), stream);
        absmax_kernel<<<256, 256, 0, stream>>>((const float4*)in, partials, scal, 64, 0);
        npart = 0;
    }
    fold_main<<<NBLK, 1024, 0, stream>>>(in, W, pe, mn, mx,
                                         partials, scal, npart, out);
}